// Round 5
// baseline (317.628 us; speedup 1.0000x reference)
//
#include <hip/hip_runtime.h>
#include <cstdint>
#include <cstddef>

#define WS_ALIGN(x) (((x) + 255) & ~(size_t)255)

#define CHUNK  4096     // edges per bucketing block
#define BSHIFT 9        // 512 nodes per coarse bucket
#define BNODES 512
#define MAXNB  512      // supports N <= 262144 (problem: N=50000 -> NB=98)
#define CAP    12288    // max edges per bucket staged in LDS (mean ~8163, sd ~90)

// ---------- pass A: per-block coarse histogram ----------
__global__ __launch_bounds__(256) void pA_hist(const int* __restrict__ dst, int* __restrict__ bh,
                                               int E, int NB, int NBLK) {
  __shared__ int hist[MAXNB];
  int t = threadIdx.x, blk = blockIdx.x;
  for (int b = t; b < NB; b += 256) hist[b] = 0;
  __syncthreads();
  int e0 = blk * CHUNK, e1 = min(E, e0 + CHUNK);
  for (int e = e0 + t; e < e1; e += 256) atomicAdd(&hist[dst[e] >> BSHIFT], 1);
  __syncthreads();
  for (int b = t; b < NB; b += 256) bh[b * NBLK + blk] = hist[b];   // bucket-major
}

// ---------- hierarchical exclusive scan of bh[M] -> scn[M] ----------
__global__ __launch_bounds__(256) void k_s1(const int* __restrict__ in, int* __restrict__ bsum, int M) {
  __shared__ int s[256];
  int t = threadIdx.x, i = blockIdx.x * 256 + t;
  s[t] = (i < M) ? in[i] : 0; __syncthreads();
  for (int d = 128; d > 0; d >>= 1) { if (t < d) s[t] += s[t + d]; __syncthreads(); }
  if (t == 0) bsum[blockIdx.x] = s[0];
}

__global__ __launch_bounds__(256) void k_s2(const int* __restrict__ bsum, int* __restrict__ boff, int nb) {
  int t = threadIdx.x;
  __shared__ int s[256];
  if (nb <= 256) {
    int v = (t < nb) ? bsum[t] : 0;
    s[t] = v; __syncthreads();
    for (int d = 1; d < 256; d <<= 1) {
      int add = (t >= d) ? s[t - d] : 0;
      __syncthreads(); s[t] += add; __syncthreads();
    }
    if (t < nb) boff[t] = s[t] - v;
  } else {
    if (t == 0) { int run = 0; for (int b = 0; b < nb; ++b) { boff[b] = run; run += bsum[b]; } }
  }
}

__global__ __launch_bounds__(256) void k_s3(const int* __restrict__ in, const int* __restrict__ boff,
                                            int* __restrict__ out, int M) {
  __shared__ int s[256];
  int t = threadIdx.x, i = blockIdx.x * 256 + t;
  int v = (i < M) ? in[i] : 0;
  s[t] = v; __syncthreads();
  for (int d = 1; d < 256; d <<= 1) {
    int add = (t >= d) ? s[t - d] : 0;
    __syncthreads(); s[t] += add; __syncthreads();
  }
  if (i < M) out[i] = s[t] - v + boff[blockIdx.x];
}

// ---------- pass C: bucket-sort each chunk in LDS, write (src,dst) runs contiguously ----------
__global__ __launch_bounds__(256) void pC_scatter(const int* __restrict__ ei, const int* __restrict__ scn,
                                                  int2* __restrict__ pairs, int E, int NB, int NBLK) {
  __shared__ int hist[MAXNB], gcur[MAXNB], cur[MAXNB], lscan[MAXNB + 1], inc[MAXNB];
  __shared__ unsigned short bmap[CHUNK];
  __shared__ int sSrc[CHUNK], sDst[CHUNK];
  int t = threadIdx.x, blk = blockIdx.x;
  for (int b = t; b < NB; b += 256) { hist[b] = 0; gcur[b] = scn[b * NBLK + blk]; }
  __syncthreads();
  int e0 = blk * CHUNK, e1 = min(E, e0 + CHUNK), cnt = e1 - e0;
  for (int e = e0 + t; e < e1; e += 256) atomicAdd(&hist[ei[E + e] >> BSHIFT], 1);
  __syncthreads();
  {
    inc[t] = (t < NB) ? hist[t] : 0;
    inc[t + 256] = (t + 256 < NB) ? hist[t + 256] : 0;
    __syncthreads();
    for (int d = 1; d < MAXNB; d <<= 1) {
      int a0 = (t >= d) ? inc[t - d] : 0;
      int a1 = (t + 256 >= d) ? inc[t + 256 - d] : 0;
      __syncthreads();
      inc[t] += a0; inc[t + 256] += a1;
      __syncthreads();
    }
    if (t == 0) lscan[0] = 0;
    lscan[t + 1] = inc[t];
    lscan[t + 257] = inc[t + 256];
    __syncthreads();
  }
  for (int b = t; b < NB; b += 256) {
    cur[b] = lscan[b];
    for (int s = lscan[b]; s < lscan[b + 1]; ++s) bmap[s] = (unsigned short)b;
  }
  __syncthreads();
  for (int e = e0 + t; e < e1; e += 256) {
    int srcv = ei[e], dstv = ei[E + e];
    int b = dstv >> BSHIFT;
    int p = atomicAdd(&cur[b], 1);
    sSrc[p] = srcv; sDst[p] = dstv;
  }
  __syncthreads();
  for (int s = t; s < cnt; s += 256) {
    int b = bmap[s];
    int g = gcur[b] + (s - lscan[b]);
    pairs[g] = make_int2(sSrc[s], sDst[s]);
  }
}

// ---------- pass D: per-bucket fine CSR ----------
__global__ __launch_bounds__(256) void pD_fine(const int2* __restrict__ pairs, const int* __restrict__ scn,
                                               int* __restrict__ perm, int* __restrict__ off,
                                               float* __restrict__ dinv, int N, int E, int NB, int NBLK) {
  __shared__ int ncnt[BNODES], ncur[BNODES];
  __shared__ int staged[CAP];
  int t = threadIdx.x, b = blockIdx.x;
  int node0 = b << BSHIFT;
  int S = scn[b * NBLK];
  int T = (b + 1 < NB) ? scn[(b + 1) * NBLK] : E;
  ncnt[t] = 0; ncnt[t + 256] = 0;
  __syncthreads();
  for (int e = S + t; e < T; e += 256) atomicAdd(&ncnt[pairs[e].y - node0], 1);
  __syncthreads();
  for (int l = t; l < BNODES; l += 256) {
    int node = node0 + l;
    if (node < N) dinv[node] = rsqrtf((float)ncnt[l] + 1.0f);   // +1 self-loop
  }
  for (int d = 1; d < BNODES; d <<= 1) {
    int a0 = (t >= d) ? ncnt[t - d] : 0;
    int a1 = (t + 256 >= d) ? ncnt[t + 256 - d] : 0;
    __syncthreads();
    ncnt[t] += a0; ncnt[t + 256] += a1;
    __syncthreads();
  }
  for (int l = t; l < BNODES; l += 256) {
    int excl = (l > 0) ? ncnt[l - 1] : 0;
    ncur[l] = excl;
    int node = node0 + l;
    if (node < N) off[node] = S + excl;
  }
  if (b == NB - 1 && t == 0) off[N] = E;
  __syncthreads();
  bool ok = (T - S) <= CAP;
  for (int e = S + t; e < T; e += 256) {
    int2 p = pairs[e];
    int pos = atomicAdd(&ncur[p.y - node0], 1);
    if (ok) staged[pos] = p.x;
    else    perm[S + pos] = p.x;
  }
  if (ok) {
    __syncthreads();
    for (int s = t; s < T - S; s += 256) perm[S + s] = staged[s];
  }
}

// ---------- GEMM v3 (lane = row): O[n][j] = (sum_k X[n][k] W[k][j]) * dinv[n] ----------
// One wave per block; lane owns a row; acc[64] in VGPRs. X tile staged coalesced into
// LDS with row stride K+1 -> per-k ds_read_b32 is conflict-free (2-way alias = free),
// delivering 64 useful floats per LDS slot. W row per k is wave-uniform -> s_load_dwordx16
// from the hot 32KB W. Inner loop: 1 ds_read + 64 FMA per k -> FMA-bound.
template<int K>
__global__ __launch_bounds__(64) void k_gemm_scale(const float* __restrict__ X, const float* __restrict__ W,
                                                   const float* __restrict__ dinv, float* __restrict__ O, int N) {
  __shared__ float Xs[64 * (K + 1)];
  const int lane = threadIdx.x;            // 0..63
  const int row0 = blockIdx.x * 64;

  // stage 64 rows, coalesced float4 reads, scalar LDS writes into padded layout
  {
    const float4* __restrict__ Xg = (const float4*)(X + (size_t)row0 * K);
    const int rows = min(64, N - row0);
    const int valid4 = rows * (K / 4);
    #pragma unroll
    for (int i = 0; i < K / 4; ++i) {
      int idx4 = i * 64 + lane;
      float4 v = (idx4 < valid4) ? Xg[idx4] : make_float4(0.f, 0.f, 0.f, 0.f);
      int r = idx4 / (K / 4), c4 = idx4 % (K / 4);
      float* d = &Xs[r * (K + 1) + c4 * 4];
      d[0] = v.x; d[1] = v.y; d[2] = v.z; d[3] = v.w;
    }
  }
  __syncthreads();

  float acc[64];
  #pragma unroll
  for (int j = 0; j < 64; ++j) acc[j] = 0.f;

  const float* __restrict__ xrow = Xs + lane * (K + 1);
  #pragma unroll 2
  for (int k = 0; k < K; ++k) {
    float xv = xrow[k];                       // ds_read_b32, conflict-free
    const float* __restrict__ wr = W + k * 64; // wave-uniform -> s_load_dwordx16 x4
    #pragma unroll
    for (int j = 0; j < 64; ++j) acc[j] = fmaf(xv, wr[j], acc[j]);
  }

  int row = row0 + lane;
  if (row < N) {
    float dv = dinv[row];
    float4* __restrict__ Og = (float4*)(O + (size_t)row * 64);
    #pragma unroll
    for (int j4 = 0; j4 < 16; ++j4)
      Og[j4] = make_float4(acc[4 * j4] * dv, acc[4 * j4 + 1] * dv,
                           acc[4 * j4 + 2] * dv, acc[4 * j4 + 3] * dv);
  }
}

// ---------- aggregation gather ----------
template<bool RELU>
__global__ __launch_bounds__(256) void k_gather(const float* __restrict__ g, const int* __restrict__ off,
                                                const int* __restrict__ perm, const float* __restrict__ dinv,
                                                const float* __restrict__ bias, float* __restrict__ z, int N) {
  int lane = threadIdx.x & 63;
  int n = blockIdx.x * 4 + (threadIdx.x >> 6);
  if (n >= N) return;
  int s0 = off[n], s1 = off[n + 1];
  float a0 = g[(size_t)n * 64 + lane], a1 = 0.f, a2 = 0.f, a3 = 0.f;
  float a4 = 0.f, a5 = 0.f, a6 = 0.f, a7 = 0.f;
  int p = s0;
  for (; p + 8 <= s1; p += 8) {           // 8 rows in flight
    int i0 = perm[p],     i1 = perm[p + 1], i2 = perm[p + 2], i3 = perm[p + 3];
    int i4 = perm[p + 4], i5 = perm[p + 5], i6 = perm[p + 6], i7 = perm[p + 7];
    a0 += g[(size_t)i0 * 64 + lane];
    a1 += g[(size_t)i1 * 64 + lane];
    a2 += g[(size_t)i2 * 64 + lane];
    a3 += g[(size_t)i3 * 64 + lane];
    a4 += g[(size_t)i4 * 64 + lane];
    a5 += g[(size_t)i5 * 64 + lane];
    a6 += g[(size_t)i6 * 64 + lane];
    a7 += g[(size_t)i7 * 64 + lane];
  }
  for (; p < s1; ++p) a0 += g[(size_t)perm[p] * 64 + lane];
  float r = dinv[n] * (((a0 + a1) + (a2 + a3)) + ((a4 + a5) + (a6 + a7))) + bias[lane];
  if (RELU) r = fmaxf(r, 0.f);
  z[(size_t)n * 64 + lane] = r;
}

// ---------- decoder: block-cooperative, 64 edges/block, 4 waves = 4 feature-quarters ----------
__global__ __launch_bounds__(256) void k_decode_fused(
    const float* __restrict__ z, const int* __restrict__ eli,
    const float* __restrict__ P1, const float* __restrict__ pb1,
    const float* __restrict__ P2, const float* __restrict__ pb2,
    const float* __restrict__ P3, const float* __restrict__ pb3,
    float* __restrict__ out, int EL) {
  __shared__ float ef[64 * 65];
  __shared__ float hs[64 * 65];
  __shared__ float part[4 * 64];
  const int t = threadIdx.x;
  const int e0 = blockIdx.x * 64;
  {
    int el = t >> 2, p = t & 3;
    int e = e0 + el;
    int ec = (e < EL) ? e : (EL - 1);
    int u = eli[ec], v = eli[EL + ec];
    const float4* zu = (const float4*)(z + (size_t)u * 64 + p * 16);
    const float4* zv = (const float4*)(z + (size_t)v * 64 + p * 16);
    float* w = &ef[el * 65 + p * 16];
    #pragma unroll
    for (int i = 0; i < 4; ++i) {
      float4 a = zu[i], b = zv[i];
      w[4 * i + 0] = a.x * b.x; w[4 * i + 1] = a.y * b.y;
      w[4 * i + 2] = a.z * b.z; w[4 * i + 3] = a.w * b.w;
    }
  }
  __syncthreads();
  const int lane = t & 63;
  const int q = __builtin_amdgcn_readfirstlane(t >> 6);
  float acc[16];
  #pragma unroll
  for (int j = 0; j < 16; ++j) acc[j] = pb1[16 * q + j];
  for (int k = 0; k < 64; ++k) {
    float efk = ef[lane * 65 + k];
    const float* __restrict__ w = P1 + k * 64 + 16 * q;
    #pragma unroll
    for (int j = 0; j < 16; ++j) acc[j] = fmaf(efk, w[j], acc[j]);
  }
  #pragma unroll
  for (int j = 0; j < 16; ++j) hs[lane * 65 + 16 * q + j] = fmaxf(acc[j], 0.f);
  __syncthreads();
  #pragma unroll
  for (int j = 0; j < 16; ++j) acc[j] = pb2[16 * q + j];
  for (int k = 0; k < 64; ++k) {
    float hk = hs[lane * 65 + k];
    const float* __restrict__ w = P2 + k * 64 + 16 * q;
    #pragma unroll
    for (int j = 0; j < 16; ++j) acc[j] = fmaf(hk, w[j], acc[j]);
  }
  float r = 0.f;
  #pragma unroll
  for (int j = 0; j < 16; ++j) r = fmaf(fmaxf(acc[j], 0.f), P3[16 * q + j], r);
  part[q * 64 + lane] = r;
  __syncthreads();
  if (t < 64) {
    int e = e0 + t;
    if (e < EL)
      out[e] = ((part[t] + part[64 + t]) + (part[128 + t] + part[192 + t])) + pb3[0];
  }
}

// ---------- host ----------
extern "C" void kernel_launch(void* const* d_in, const int* in_sizes, int n_in,
                              void* d_out, int out_size, void* d_ws, size_t ws_size,
                              hipStream_t stream) {
  const float* x   = (const float*)d_in[0];
  const int*   ei  = (const int*)d_in[1];
  const int*   eli = (const int*)d_in[2];
  const float* W1  = (const float*)d_in[3];
  const float* b1  = (const float*)d_in[4];
  const float* W2  = (const float*)d_in[5];
  const float* b2  = (const float*)d_in[6];
  const float* P1  = (const float*)d_in[7];
  const float* pb1 = (const float*)d_in[8];
  const float* P2  = (const float*)d_in[9];
  const float* pb2 = (const float*)d_in[10];
  const float* P3  = (const float*)d_in[11];
  const float* pb3 = (const float*)d_in[12];
  float* out = (float*)d_out;

  const int N  = in_sizes[0] / 128;
  const int E  = in_sizes[1] / 2;
  const int EL = in_sizes[2] / 2;

  const int NB   = (N + BNODES - 1) >> BSHIFT;
  const int NBLK = (E + CHUNK - 1) / CHUNK;
  const int M    = NB * NBLK;
  const int nb2  = (M + 255) / 256;

  char* w = (char*)d_ws;
  auto alloc = [&](size_t bytes) { char* p = w; w += WS_ALIGN(bytes); return p; };
  int*   bh    = (int*)  alloc((size_t)M * 4);
  int*   scn   = (int*)  alloc((size_t)M * 4);
  int*   bsum  = (int*)  alloc(1024 * 4);
  int*   boff  = (int*)  alloc(1024 * 4);
  int2*  pairs = (int2*) alloc((size_t)E * 8);
  int*   perm  = (int*)  alloc((size_t)E * 4);
  int*   off   = (int*)  alloc(((size_t)N + 1) * 4);
  float* dinv  = (float*)alloc((size_t)N * 4);
  float* bufA  = (float*)alloc((size_t)N * 64 * 4);
  float* bufB  = (float*)alloc((size_t)N * 64 * 4);

  hipLaunchKernelGGL(pA_hist,    dim3(NBLK), dim3(256), 0, stream, ei + E, bh, E, NB, NBLK);
  hipLaunchKernelGGL(k_s1,       dim3(nb2),  dim3(256), 0, stream, bh, bsum, M);
  hipLaunchKernelGGL(k_s2,       dim3(1),    dim3(256), 0, stream, bsum, boff, nb2);
  hipLaunchKernelGGL(k_s3,       dim3(nb2),  dim3(256), 0, stream, bh, boff, scn, M);
  hipLaunchKernelGGL(pC_scatter, dim3(NBLK), dim3(256), 0, stream, ei, scn, pairs, E, NB, NBLK);
  hipLaunchKernelGGL(pD_fine,    dim3(NB),   dim3(256), 0, stream, pairs, scn, perm, off, dinv, N, E, NB, NBLK);

  hipLaunchKernelGGL((k_gemm_scale<128>), dim3((N + 63) / 64), dim3(64), 0, stream, x, W1, dinv, bufA, N);
  hipLaunchKernelGGL((k_gather<true>),    dim3((N + 3) / 4),   dim3(256), 0, stream, bufA, off, perm, dinv, b1, bufB, N);
  hipLaunchKernelGGL((k_gemm_scale<64>),  dim3((N + 63) / 64), dim3(64), 0, stream, bufB, W2, dinv, bufA, N);
  hipLaunchKernelGGL((k_gather<false>),   dim3((N + 3) / 4),   dim3(256), 0, stream, bufA, off, perm, dinv, b2, bufB, N);
  hipLaunchKernelGGL(k_decode_fused, dim3((EL + 63) / 64), dim3(256), 0, stream,
                     bufB, eli, P1, pb1, P2, pb2, P3, pb3, out, EL);
}

// Round 6
// 272.066 us; speedup vs baseline: 1.1675x; 1.1675x over previous
//
#include <hip/hip_runtime.h>
#include <cstdint>
#include <cstddef>

#define WS_ALIGN(x) (((x) + 255) & ~(size_t)255)

#define CHUNK  4096     // edges per bucketing block
#define BSHIFT 9        // 512 nodes per coarse bucket
#define BNODES 512
#define MAXNB  512      // supports N <= 262144 (problem: N=50000 -> NB=98)
#define CAP    12288    // max edges per bucket staged in LDS (mean ~8163, sd ~90)

// ---------- pass A: per-block coarse histogram ----------
__global__ __launch_bounds__(256) void pA_hist(const int* __restrict__ dst, int* __restrict__ bh,
                                               int E, int NB, int NBLK) {
  __shared__ int hist[MAXNB];
  int t = threadIdx.x, blk = blockIdx.x;
  for (int b = t; b < NB; b += 256) hist[b] = 0;
  __syncthreads();
  int e0 = blk * CHUNK, e1 = min(E, e0 + CHUNK);
  for (int e = e0 + t; e < e1; e += 256) atomicAdd(&hist[dst[e] >> BSHIFT], 1);
  __syncthreads();
  for (int b = t; b < NB; b += 256) bh[b * NBLK + blk] = hist[b];   // bucket-major
}

// ---------- hierarchical exclusive scan of bh[M] -> scn[M] ----------
__global__ __launch_bounds__(256) void k_s1(const int* __restrict__ in, int* __restrict__ bsum, int M) {
  __shared__ int s[256];
  int t = threadIdx.x, i = blockIdx.x * 256 + t;
  s[t] = (i < M) ? in[i] : 0; __syncthreads();
  for (int d = 128; d > 0; d >>= 1) { if (t < d) s[t] += s[t + d]; __syncthreads(); }
  if (t == 0) bsum[blockIdx.x] = s[0];
}

__global__ __launch_bounds__(256) void k_s2(const int* __restrict__ bsum, int* __restrict__ boff, int nb) {
  int t = threadIdx.x;
  __shared__ int s[256];
  if (nb <= 256) {
    int v = (t < nb) ? bsum[t] : 0;
    s[t] = v; __syncthreads();
    for (int d = 1; d < 256; d <<= 1) {
      int add = (t >= d) ? s[t - d] : 0;
      __syncthreads(); s[t] += add; __syncthreads();
    }
    if (t < nb) boff[t] = s[t] - v;
  } else {
    if (t == 0) { int run = 0; for (int b = 0; b < nb; ++b) { boff[b] = run; run += bsum[b]; } }
  }
}

__global__ __launch_bounds__(256) void k_s3(const int* __restrict__ in, const int* __restrict__ boff,
                                            int* __restrict__ out, int M) {
  __shared__ int s[256];
  int t = threadIdx.x, i = blockIdx.x * 256 + t;
  int v = (i < M) ? in[i] : 0;
  s[t] = v; __syncthreads();
  for (int d = 1; d < 256; d <<= 1) {
    int add = (t >= d) ? s[t - d] : 0;
    __syncthreads(); s[t] += add; __syncthreads();
  }
  if (i < M) out[i] = s[t] - v + boff[blockIdx.x];
}

// ---------- pass C: bucket-sort each chunk in LDS, write (src,dst) runs contiguously ----------
__global__ __launch_bounds__(256) void pC_scatter(const int* __restrict__ ei, const int* __restrict__ scn,
                                                  int2* __restrict__ pairs, int E, int NB, int NBLK) {
  __shared__ int hist[MAXNB], gcur[MAXNB], cur[MAXNB], lscan[MAXNB + 1], inc[MAXNB];
  __shared__ unsigned short bmap[CHUNK];
  __shared__ int sSrc[CHUNK], sDst[CHUNK];
  int t = threadIdx.x, blk = blockIdx.x;
  for (int b = t; b < NB; b += 256) { hist[b] = 0; gcur[b] = scn[b * NBLK + blk]; }
  __syncthreads();
  int e0 = blk * CHUNK, e1 = min(E, e0 + CHUNK), cnt = e1 - e0;
  for (int e = e0 + t; e < e1; e += 256) atomicAdd(&hist[ei[E + e] >> BSHIFT], 1);
  __syncthreads();
  {
    inc[t] = (t < NB) ? hist[t] : 0;
    inc[t + 256] = (t + 256 < NB) ? hist[t + 256] : 0;
    __syncthreads();
    for (int d = 1; d < MAXNB; d <<= 1) {
      int a0 = (t >= d) ? inc[t - d] : 0;
      int a1 = (t + 256 >= d) ? inc[t + 256 - d] : 0;
      __syncthreads();
      inc[t] += a0; inc[t + 256] += a1;
      __syncthreads();
    }
    if (t == 0) lscan[0] = 0;
    lscan[t + 1] = inc[t];
    lscan[t + 257] = inc[t + 256];
    __syncthreads();
  }
  for (int b = t; b < NB; b += 256) {
    cur[b] = lscan[b];
    for (int s = lscan[b]; s < lscan[b + 1]; ++s) bmap[s] = (unsigned short)b;
  }
  __syncthreads();
  for (int e = e0 + t; e < e1; e += 256) {
    int srcv = ei[e], dstv = ei[E + e];
    int b = dstv >> BSHIFT;
    int p = atomicAdd(&cur[b], 1);
    sSrc[p] = srcv; sDst[p] = dstv;
  }
  __syncthreads();
  for (int s = t; s < cnt; s += 256) {
    int b = bmap[s];
    int g = gcur[b] + (s - lscan[b]);
    pairs[g] = make_int2(sSrc[s], sDst[s]);
  }
}

// ---------- pass D: per-bucket fine CSR ----------
__global__ __launch_bounds__(256) void pD_fine(const int2* __restrict__ pairs, const int* __restrict__ scn,
                                               int* __restrict__ perm, int* __restrict__ off,
                                               float* __restrict__ dinv, int N, int E, int NB, int NBLK) {
  __shared__ int ncnt[BNODES], ncur[BNODES];
  __shared__ int staged[CAP];
  int t = threadIdx.x, b = blockIdx.x;
  int node0 = b << BSHIFT;
  int S = scn[b * NBLK];
  int T = (b + 1 < NB) ? scn[(b + 1) * NBLK] : E;
  ncnt[t] = 0; ncnt[t + 256] = 0;
  __syncthreads();
  for (int e = S + t; e < T; e += 256) atomicAdd(&ncnt[pairs[e].y - node0], 1);
  __syncthreads();
  for (int l = t; l < BNODES; l += 256) {
    int node = node0 + l;
    if (node < N) dinv[node] = rsqrtf((float)ncnt[l] + 1.0f);   // +1 self-loop
  }
  for (int d = 1; d < BNODES; d <<= 1) {
    int a0 = (t >= d) ? ncnt[t - d] : 0;
    int a1 = (t + 256 >= d) ? ncnt[t + 256 - d] : 0;
    __syncthreads();
    ncnt[t] += a0; ncnt[t + 256] += a1;
    __syncthreads();
  }
  for (int l = t; l < BNODES; l += 256) {
    int excl = (l > 0) ? ncnt[l - 1] : 0;
    ncur[l] = excl;
    int node = node0 + l;
    if (node < N) off[node] = S + excl;
  }
  if (b == NB - 1 && t == 0) off[N] = E;
  __syncthreads();
  bool ok = (T - S) <= CAP;
  for (int e = S + t; e < T; e += 256) {
    int2 p = pairs[e];
    int pos = atomicAdd(&ncur[p.y - node0], 1);
    if (ok) staged[pos] = p.x;
    else    perm[S + pos] = p.x;
  }
  if (ok) {
    __syncthreads();
    for (int s = t; s < T - S; s += 256) perm[S + s] = staged[s];
  }
}

// ---------- GEMM v4: 256 threads, 64-row LDS tile, wave q owns cols [16q,16q+16) ----------
// Thread = (row = lane, 16 cols). Per k: 1 conflict-free ds_read_b32 (X, stride K+1)
// + 1 wave-uniform s_load_dwordx16 (W row slice) + 16 FMA -> VALU-bound.
// 33 KB LDS (K=128) -> 4 blocks/CU = 16 waves/CU for latency hiding.
template<int K>
__global__ __launch_bounds__(256) void k_gemm_scale(const float* __restrict__ X, const float* __restrict__ W,
                                                    const float* __restrict__ dinv, float* __restrict__ O, int N) {
  __shared__ float Xs[64 * (K + 1)];
  const int t = threadIdx.x;
  const int r = t & 63;                                          // row within tile
  const int q = __builtin_amdgcn_readfirstlane(t >> 6);          // col group, wave-uniform
  const int row0 = blockIdx.x * 64;

  // stage 64 rows, coalesced float4 reads into padded layout
  {
    const float4* __restrict__ Xg = (const float4*)(X + (size_t)row0 * K);
    const int rows = min(64, N - row0);
    const int valid4 = rows * (K / 4);
    const int total4 = 64 * (K / 4);
    for (int i = t; i < total4; i += 256) {
      float4 v = (i < valid4) ? Xg[i] : make_float4(0.f, 0.f, 0.f, 0.f);
      int rr = i / (K / 4), c4 = i % (K / 4);
      float* d = &Xs[rr * (K + 1) + c4 * 4];
      d[0] = v.x; d[1] = v.y; d[2] = v.z; d[3] = v.w;
    }
  }
  __syncthreads();

  float acc[16];
  #pragma unroll
  for (int j = 0; j < 16; ++j) acc[j] = 0.f;

  const float* __restrict__ xrow = Xs + r * (K + 1);
  const float* __restrict__ Wq = W + q * 16;
  #pragma unroll 4
  for (int k = 0; k < K; ++k) {
    float xv = xrow[k];                         // ds_read_b32, (r+k)%32 banks: 2-way = free
    const float* __restrict__ wr = Wq + k * 64; // wave-uniform -> s_load_dwordx16
    #pragma unroll
    for (int j = 0; j < 16; ++j) acc[j] = fmaf(xv, wr[j], acc[j]);
  }

  int row = row0 + r;
  if (row < N) {
    float dv = dinv[row];
    float4* __restrict__ Og = (float4*)(O + (size_t)row * 64 + q * 16);
    #pragma unroll
    for (int j4 = 0; j4 < 4; ++j4)
      Og[j4] = make_float4(acc[4 * j4] * dv, acc[4 * j4 + 1] * dv,
                           acc[4 * j4 + 2] * dv, acc[4 * j4 + 3] * dv);
  }
}

// ---------- aggregation gather ----------
template<bool RELU>
__global__ __launch_bounds__(256) void k_gather(const float* __restrict__ g, const int* __restrict__ off,
                                                const int* __restrict__ perm, const float* __restrict__ dinv,
                                                const float* __restrict__ bias, float* __restrict__ z, int N) {
  int lane = threadIdx.x & 63;
  int n = blockIdx.x * 4 + (threadIdx.x >> 6);
  if (n >= N) return;
  int s0 = off[n], s1 = off[n + 1];
  float a0 = g[(size_t)n * 64 + lane], a1 = 0.f, a2 = 0.f, a3 = 0.f;
  float a4 = 0.f, a5 = 0.f, a6 = 0.f, a7 = 0.f;
  int p = s0;
  for (; p + 8 <= s1; p += 8) {           // 8 rows in flight
    int i0 = perm[p],     i1 = perm[p + 1], i2 = perm[p + 2], i3 = perm[p + 3];
    int i4 = perm[p + 4], i5 = perm[p + 5], i6 = perm[p + 6], i7 = perm[p + 7];
    a0 += g[(size_t)i0 * 64 + lane];
    a1 += g[(size_t)i1 * 64 + lane];
    a2 += g[(size_t)i2 * 64 + lane];
    a3 += g[(size_t)i3 * 64 + lane];
    a4 += g[(size_t)i4 * 64 + lane];
    a5 += g[(size_t)i5 * 64 + lane];
    a6 += g[(size_t)i6 * 64 + lane];
    a7 += g[(size_t)i7 * 64 + lane];
  }
  for (; p < s1; ++p) a0 += g[(size_t)perm[p] * 64 + lane];
  float r = dinv[n] * (((a0 + a1) + (a2 + a3)) + ((a4 + a5) + (a6 + a7))) + bias[lane];
  if (RELU) r = fmaxf(r, 0.f);
  z[(size_t)n * 64 + lane] = r;
}

// ---------- decoder: block-cooperative, 64 edges/block, 4 waves = 4 feature-quarters ----------
__global__ __launch_bounds__(256) void k_decode_fused(
    const float* __restrict__ z, const int* __restrict__ eli,
    const float* __restrict__ P1, const float* __restrict__ pb1,
    const float* __restrict__ P2, const float* __restrict__ pb2,
    const float* __restrict__ P3, const float* __restrict__ pb3,
    float* __restrict__ out, int EL) {
  __shared__ float ef[64 * 65];
  __shared__ float hs[64 * 65];
  __shared__ float part[4 * 64];
  const int t = threadIdx.x;
  const int e0 = blockIdx.x * 64;
  {
    int el = t >> 2, p = t & 3;
    int e = e0 + el;
    int ec = (e < EL) ? e : (EL - 1);
    int u = eli[ec], v = eli[EL + ec];
    const float4* zu = (const float4*)(z + (size_t)u * 64 + p * 16);
    const float4* zv = (const float4*)(z + (size_t)v * 64 + p * 16);
    float* w = &ef[el * 65 + p * 16];
    #pragma unroll
    for (int i = 0; i < 4; ++i) {
      float4 a = zu[i], b = zv[i];
      w[4 * i + 0] = a.x * b.x; w[4 * i + 1] = a.y * b.y;
      w[4 * i + 2] = a.z * b.z; w[4 * i + 3] = a.w * b.w;
    }
  }
  __syncthreads();
  const int lane = t & 63;
  const int q = __builtin_amdgcn_readfirstlane(t >> 6);
  float acc[16];
  #pragma unroll
  for (int j = 0; j < 16; ++j) acc[j] = pb1[16 * q + j];
  for (int k = 0; k < 64; ++k) {
    float efk = ef[lane * 65 + k];
    const float* __restrict__ w = P1 + k * 64 + 16 * q;
    #pragma unroll
    for (int j = 0; j < 16; ++j) acc[j] = fmaf(efk, w[j], acc[j]);
  }
  #pragma unroll
  for (int j = 0; j < 16; ++j) hs[lane * 65 + 16 * q + j] = fmaxf(acc[j], 0.f);
  __syncthreads();
  #pragma unroll
  for (int j = 0; j < 16; ++j) acc[j] = pb2[16 * q + j];
  for (int k = 0; k < 64; ++k) {
    float hk = hs[lane * 65 + k];
    const float* __restrict__ w = P2 + k * 64 + 16 * q;
    #pragma unroll
    for (int j = 0; j < 16; ++j) acc[j] = fmaf(hk, w[j], acc[j]);
  }
  float r = 0.f;
  #pragma unroll
  for (int j = 0; j < 16; ++j) r = fmaf(fmaxf(acc[j], 0.f), P3[16 * q + j], r);
  part[q * 64 + lane] = r;
  __syncthreads();
  if (t < 64) {
    int e = e0 + t;
    if (e < EL)
      out[e] = ((part[t] + part[64 + t]) + (part[128 + t] + part[192 + t])) + pb3[0];
  }
}

// ---------- host ----------
extern "C" void kernel_launch(void* const* d_in, const int* in_sizes, int n_in,
                              void* d_out, int out_size, void* d_ws, size_t ws_size,
                              hipStream_t stream) {
  const float* x   = (const float*)d_in[0];
  const int*   ei  = (const int*)d_in[1];
  const int*   eli = (const int*)d_in[2];
  const float* W1  = (const float*)d_in[3];
  const float* b1  = (const float*)d_in[4];
  const float* W2  = (const float*)d_in[5];
  const float* b2  = (const float*)d_in[6];
  const float* P1  = (const float*)d_in[7];
  const float* pb1 = (const float*)d_in[8];
  const float* P2  = (const float*)d_in[9];
  const float* pb2 = (const float*)d_in[10];
  const float* P3  = (const float*)d_in[11];
  const float* pb3 = (const float*)d_in[12];
  float* out = (float*)d_out;

  const int N  = in_sizes[0] / 128;
  const int E  = in_sizes[1] / 2;
  const int EL = in_sizes[2] / 2;

  const int NB   = (N + BNODES - 1) >> BSHIFT;
  const int NBLK = (E + CHUNK - 1) / CHUNK;
  const int M    = NB * NBLK;
  const int nb2  = (M + 255) / 256;

  char* w = (char*)d_ws;
  auto alloc = [&](size_t bytes) { char* p = w; w += WS_ALIGN(bytes); return p; };
  int*   bh    = (int*)  alloc((size_t)M * 4);
  int*   scn   = (int*)  alloc((size_t)M * 4);
  int*   bsum  = (int*)  alloc(1024 * 4);
  int*   boff  = (int*)  alloc(1024 * 4);
  int2*  pairs = (int2*) alloc((size_t)E * 8);
  int*   perm  = (int*)  alloc((size_t)E * 4);
  int*   off   = (int*)  alloc(((size_t)N + 1) * 4);
  float* dinv  = (float*)alloc((size_t)N * 4);
  float* bufA  = (float*)alloc((size_t)N * 64 * 4);
  float* bufB  = (float*)alloc((size_t)N * 64 * 4);

  hipLaunchKernelGGL(pA_hist,    dim3(NBLK), dim3(256), 0, stream, ei + E, bh, E, NB, NBLK);
  hipLaunchKernelGGL(k_s1,       dim3(nb2),  dim3(256), 0, stream, bh, bsum, M);
  hipLaunchKernelGGL(k_s2,       dim3(1),    dim3(256), 0, stream, bsum, boff, nb2);
  hipLaunchKernelGGL(k_s3,       dim3(nb2),  dim3(256), 0, stream, bh, boff, scn, M);
  hipLaunchKernelGGL(pC_scatter, dim3(NBLK), dim3(256), 0, stream, ei, scn, pairs, E, NB, NBLK);
  hipLaunchKernelGGL(pD_fine,    dim3(NB),   dim3(256), 0, stream, pairs, scn, perm, off, dinv, N, E, NB, NBLK);

  hipLaunchKernelGGL((k_gemm_scale<128>), dim3((N + 63) / 64), dim3(256), 0, stream, x, W1, dinv, bufA, N);
  hipLaunchKernelGGL((k_gather<true>),    dim3((N + 3) / 4),   dim3(256), 0, stream, bufA, off, perm, dinv, b1, bufB, N);
  hipLaunchKernelGGL((k_gemm_scale<64>),  dim3((N + 63) / 64), dim3(256), 0, stream, bufB, W2, dinv, bufA, N);
  hipLaunchKernelGGL((k_gather<false>),   dim3((N + 3) / 4),   dim3(256), 0, stream, bufA, off, perm, dinv, b2, bufB, N);
  hipLaunchKernelGGL(k_decode_fused, dim3((EL + 63) / 64), dim3(256), 0, stream,
                     bufB, eli, P1, pb1, P2, pb2, P3, pb3, out, EL);
}